// Round 4
// baseline (434.779 us; speedup 1.0000x reference)
//
#include <hip/hip_runtime.h>
#include <cstdint>
#include <cstddef>

typedef _Float16 f16;
typedef __attribute__((ext_vector_type(8))) _Float16 half8;
typedef __attribute__((ext_vector_type(8))) short short8;
typedef __attribute__((ext_vector_type(4))) float floatx4;

#define KDIM 256

__device__ __forceinline__ float sigm(float x) { return 1.0f / (1.0f + __expf(-x)); }

// C[M,N] = A[M,256] @ BT[N,256]^T ; fp16 in/out, fp32 accum. 64x64 tile/block.
// Caller guarantees gridDim.x*64 readable A rows / writable C rows; N mult of 64.
__global__ __launch_bounds__(256) void gemm16(
    const f16* __restrict__ A, const f16* __restrict__ BT,
    f16* __restrict__ C, int ldc_)
{
  __shared__ short lA[64 * 136];
  __shared__ short lB[64 * 136];
  const int t = threadIdx.x;
  const int m0 = blockIdx.x * 64;
  const int n0 = blockIdx.y * 64;
  const int wave = t >> 6;
  const int lane = t & 63;
  const int ln = lane & 15;
  const int quad = lane >> 4;

  floatx4 acc[4];
#pragma unroll
  for (int i = 0; i < 4; ++i) acc[i] = (floatx4){0.f, 0.f, 0.f, 0.f};

#pragma unroll
  for (int kh = 0; kh < 2; ++kh) {
    const int k0 = kh * 128;
#pragma unroll
    for (int i = 0; i < 4; ++i) {
      int chunk = t + 256 * i;      // 64 rows x 16 chunks of 8 halves = 64x128
      int row = chunk >> 4;
      int cc = chunk & 15;
      *(short8*)&lA[row * 136 + cc * 8] =
          *(const short8*)(A + (size_t)(m0 + row) * KDIM + k0 + cc * 8);
      *(short8*)&lB[row * 136 + cc * 8] =
          *(const short8*)(BT + (size_t)(n0 + row) * KDIM + k0 + cc * 8);
    }
    __syncthreads();
#pragma unroll
    for (int ks = 0; ks < 4; ++ks) {
      const int kk = ks * 32 + quad * 8;
      half8 a = __builtin_bit_cast(half8,
          *(const short8*)&lA[(wave * 16 + ln) * 136 + kk]);
#pragma unroll
      for (int c = 0; c < 4; ++c) {
        half8 b = __builtin_bit_cast(half8,
            *(const short8*)&lB[(c * 16 + ln) * 136 + kk]);
        acc[c] = __builtin_amdgcn_mfma_f32_16x16x32_f16(a, b, acc[c], 0, 0, 0);
      }
    }
    __syncthreads();
  }
  // D layout: col = lane&15, row = quad*4 + reg
#pragma unroll
  for (int c = 0; c < 4; ++c) {
#pragma unroll
    for (int r = 0; r < 4; ++r) {
      int row = m0 + wave * 16 + quad * 4 + r;
      int col = n0 + c * 16 + ln;
      C[(size_t)row * ldc_ + col] = (f16)acc[c][r];
    }
  }
}

// fp32 inputs -> fp16 working copies: emb_h[32000x256];
// BTX[1024,256] rows 0..767 = Wioux^T, 768..1023 = Wfx^T;
// WiouhT[768,256]; WfhT[256,256]
__global__ __launch_bounds__(256) void prep(
    const float* __restrict__ emb, const float* __restrict__ Wioux,
    const float* __restrict__ Wfx, const float* __restrict__ Wiouh,
    const float* __restrict__ Wfh,
    f16* __restrict__ emb_h, f16* __restrict__ BTX,
    f16* __restrict__ WiouhT, f16* __restrict__ WfhT)
{
  int idx = blockIdx.x * 256 + threadIdx.x;   // 34048 blocks = 8,716,288
  if (idx < 8192000) {
    emb_h[idx] = (f16)emb[idx];
  } else if (idx < 8454144) {
    int r = idx - 8192000;                    // BTX
    int j = r >> 8, k = r & 255;
    BTX[r] = (f16)((j < 768) ? Wioux[(size_t)k * 768 + j]
                             : Wfx[(size_t)k * 256 + (j - 768)]);
  } else if (idx < 8650752) {
    int r = idx - 8454144;                    // WiouhT
    int j = r >> 8, k = r & 255;
    WiouhT[r] = (f16)Wiouh[(size_t)k * 768 + j];
  } else {
    int r = idx - 8650752;                    // WfhT
    int j = r >> 8, k = r & 255;
    WfhT[r] = (f16)Wfh[(size_t)k * 256 + j];
  }
}

// hsum[r] = sum of 4 children's fp32 h -> fp16 (GEMM A input)
__global__ __launch_bounds__(256) void gather_hsum(
    const float* __restrict__ h, f16* __restrict__ hs, int s)
{
  int r = blockIdx.x;
  int m = threadIdx.x;
  size_t c0 = 4 * (size_t)(s + r) + 1;
  float v = h[c0 * 256 + m] + h[(c0 + 1) * 256 + m] +
            h[(c0 + 2) * 256 + m] + h[(c0 + 3) * 256 + m];
  hs[(size_t)r * 256 + m] = (f16)v;
}

__global__ __launch_bounds__(256) void elem_leaf(
    const int* __restrict__ tokens, const f16* __restrict__ TIOUF,
    const float* __restrict__ bioux, const float* __restrict__ biouh,
    float* __restrict__ cbuf, float* __restrict__ h, f16* __restrict__ h16,
    int s)
{
  int node = s + blockIdx.x;
  int m = threadIdx.x;
  int tok = tokens[node];
  const f16* ti = TIOUF + (size_t)tok * 1024;
  float ip = (float)ti[m]       + bioux[m]       + biouh[m];
  float op = (float)ti[256 + m] + bioux[256 + m] + biouh[256 + m];
  float up = (float)ti[512 + m] + bioux[512 + m] + biouh[512 + m];
  float cv = sigm(ip) * tanhf(up);
  float hv = sigm(op) * tanhf(cv);
  cbuf[(size_t)node * 256 + m] = cv;
  h[(size_t)node * 256 + m] = hv;
  h16[(size_t)node * 256 + m] = (f16)hv;
}

__global__ __launch_bounds__(256) void elem_internal(
    const int* __restrict__ tokens, const f16* __restrict__ TIOUF,
    const f16* __restrict__ IOUH, const f16* __restrict__ FH,
    const float* __restrict__ bioux, const float* __restrict__ biouh,
    const float* __restrict__ bfx, const float* __restrict__ bfh,
    float* __restrict__ cbuf, float* __restrict__ h, f16* __restrict__ h16,
    int s)
{
  int r = blockIdx.x;
  int node = s + r;
  int m = threadIdx.x;
  int tok = tokens[node];
  const f16* ti = TIOUF + (size_t)tok * 1024;
  const f16* io = IOUH + (size_t)r * 768;
  float ip = (float)ti[m]       + (float)io[m]       + bioux[m]       + biouh[m];
  float op = (float)ti[256 + m] + (float)io[256 + m] + bioux[256 + m] + biouh[256 + m];
  float up = (float)ti[512 + m] + (float)io[512 + m] + bioux[512 + m] + biouh[512 + m];
  float xff = (float)ti[768 + m] + bfx[m] + bfh[m];
  float cv = sigm(ip) * tanhf(up);
  size_t child = 4 * (size_t)node + 1;
#pragma unroll
  for (int k = 0; k < 4; ++k) {
    float fk = sigm((float)FH[(child + k) * 256 + m] + xff);
    cv += fk * cbuf[(child + k) * 256 + m];
  }
  float hv = sigm(op) * tanhf(cv);
  cbuf[(size_t)node * 256 + m] = cv;
  h[(size_t)node * 256 + m] = hv;
  h16[(size_t)node * 256 + m] = (f16)hv;
}

extern "C" void kernel_launch(void* const* d_in, const int* in_sizes, int n_in,
                              void* d_out, int out_size, void* d_ws, size_t ws_size,
                              hipStream_t stream) {
  const int*   tokens = (const int*)d_in[0];
  const float* emb    = (const float*)d_in[2];
  const float* Wioux  = (const float*)d_in[3];
  const float* bioux  = (const float*)d_in[4];
  const float* Wiouh  = (const float*)d_in[5];
  const float* biouh  = (const float*)d_in[6];
  const float* Wfx    = (const float*)d_in[7];
  const float* bfx    = (const float*)d_in[8];
  const float* Wfh    = (const float*)d_in[9];
  const float* bfh    = (const float*)d_in[10];
  float* h = (float*)d_out;   // fp32 h master lives in d_out [87381,256]
  (void)in_sizes; (void)n_in; (void)out_size; (void)ws_size;

  // workspace (fp16 elements unless noted; ~296 MB total, proven footprint)
  f16* emb_h  = (f16*)d_ws;                      //  8,192,000
  f16* BTX    = emb_h  + 8192000;                //    262,144
  f16* WiouhT = BTX    + 262144;                 //    196,608
  f16* WfhT   = WiouhT + 196608;                 //     65,536
  f16* TIOUF  = WfhT   + 65536;                  // 32,768,000 (32000x1024)
  f16* h16    = TIOUF  + (size_t)32768000;       // 22,396,928 (87488x256)
  f16* hs     = h16    + (size_t)22396928;       //  4,194,304 (16384x256)
  f16* IOUH   = hs     + (size_t)4194304;        // 12,582,912 (16384x768)
  f16* FH     = IOUH   + (size_t)12582912;       // 22,396,928 (87488x256)
  float* cbuf = (float*)(FH + (size_t)22396928); // 87488x256 fp32

  // 0. convert inputs to fp16 working copies (weights transposed K-contiguous)
  prep<<<34048, 256, 0, stream>>>(emb, Wioux, Wfx, Wiouh, Wfh,
                                  emb_h, BTX, WiouhT, WfhT);

  // 1. vocab table: TIOUF[v] = emb[v] @ [Wioux | Wfx]   (32000 x 1024)
  gemm16<<<dim3(500, 16), 256, 0, stream>>>(emb_h, BTX, TIOUF, 1024);

  // 2. leaves (s=21845, sz=65536)
  elem_leaf<<<65536, 256, 0, stream>>>(tokens, TIOUF, bioux, biouh,
                                       cbuf, h, h16, 21845);
  gemm16<<<dim3(1024, 4), 256, 0, stream>>>(
      h16 + (size_t)21845 * 256, WfhT, FH + (size_t)21845 * 256, 256);

  // 3. internal levels, leaves-1 up to root
  const int LS[8][2] = {{5461, 16384}, {1365, 4096}, {341, 1024}, {85, 256},
                        {21, 64},      {5, 16},      {1, 4},      {0, 1}};
  for (int i = 0; i < 8; ++i) {
    int s = LS[i][0], sz = LS[i][1];
    int mt = (sz + 63) / 64;
    gather_hsum<<<sz, 256, 0, stream>>>(h, hs, s);
    gemm16<<<dim3(mt, 12), 256, 0, stream>>>(hs, WiouhT, IOUH, 768);
    elem_internal<<<sz, 256, 0, stream>>>(tokens, TIOUF, IOUH, FH,
                                          bioux, biouh, bfx, bfh,
                                          cbuf, h, h16, s);
    if (s > 0)
      gemm16<<<dim3(mt, 4), 256, 0, stream>>>(
          h16 + (size_t)s * 256, WfhT, FH + (size_t)s * 256, 256);
  }
}